// Round 2
// baseline (479.411 us; speedup 1.0000x reference)
//
#include <hip/hip_runtime.h>
#include <math.h>

// x: (4,16,256,32,64) f32 -> NS=64 samples, CD=256 channels, HW=2048 positions
#define NS 64
#define CD 256
#define HW 2048
#define MD 1024
#define SAMPLE (CD * HW)
#define LN_EPS 1e-5f

#define PB 128          // positions per block
#define MC 128          // m-chunk
#define NCHUNK (MD / MC) // 8

typedef float f32x4 __attribute__((ext_vector_type(4)));
typedef long i64;

// XOR swizzle key for 16B-slot spreading (returns pre-shifted byte key, bits 4-6)
__device__ __forceinline__ int swz(int p) { return ((p ^ (p >> 2)) & 7) << 4; }

// ---------------- weight prep: f32 -> fp8 e4m3, transposed ----------------
// w_in (c,m) -> w_in8 [m][c] ; w_out (m,c) -> w_out8 [c][m]
__global__ __launch_bounds__(256) void k_prep(const float* __restrict__ w_in,
                                              const float* __restrict__ w_out,
                                              unsigned char* __restrict__ w_in8,
                                              unsigned char* __restrict__ w_out8) {
  int id = blockIdx.x * 256 + threadIdx.x;  // 0..131071
  if (id < 65536) {
    int m = id >> 6, c0 = (id & 63) * 4;
    float a = w_in[(size_t)(c0 + 0) * MD + m];
    float b = w_in[(size_t)(c0 + 1) * MD + m];
    float c = w_in[(size_t)(c0 + 2) * MD + m];
    float d = w_in[(size_t)(c0 + 3) * MD + m];
    int r = __builtin_amdgcn_cvt_pk_fp8_f32(a, b, 0, false);
    r = __builtin_amdgcn_cvt_pk_fp8_f32(c, d, r, true);
    ((int*)w_in8)[id] = r;  // byte offset m*256 + c0
  } else {
    int j = id - 65536;
    int c = j >> 8, m0 = (j & 255) * 4;
    float a = w_out[(size_t)(m0 + 0) * CD + c];
    float b = w_out[(size_t)(m0 + 1) * CD + c];
    float cc = w_out[(size_t)(m0 + 2) * CD + c];
    float d = w_out[(size_t)(m0 + 3) * CD + c];
    int r = __builtin_amdgcn_cvt_pk_fp8_f32(a, b, 0, false);
    r = __builtin_amdgcn_cvt_pk_fp8_f32(cc, d, r, true);
    ((int*)w_out8)[j] = r;  // byte offset c*1024 + m0
  }
}

// ---------------- LN stats, stage 1: partial sums ----------------
__global__ __launch_bounds__(256) void k_stats1(const float* __restrict__ x,
                                                double* __restrict__ partial) {
  int s = blockIdx.x >> 3, sl = blockIdx.x & 7;
  const float4* p = (const float4*)(x + (size_t)s * SAMPLE + (size_t)sl * 65536);
  double sum = 0.0, ssq = 0.0;
  for (int i = 0; i < 64; ++i) {
    float4 v = p[i * 256 + threadIdx.x];
    sum += (double)v.x + (double)v.y + (double)v.z + (double)v.w;
    ssq += (double)v.x * v.x + (double)v.y * v.y + (double)v.z * v.z + (double)v.w * v.w;
  }
  for (int off = 32; off; off >>= 1) {
    sum += __shfl_down(sum, off);
    ssq += __shfl_down(ssq, off);
  }
  __shared__ double red[4][2];
  int wv = threadIdx.x >> 6, ln = threadIdx.x & 63;
  if (ln == 0) { red[wv][0] = sum; red[wv][1] = ssq; }
  __syncthreads();
  if (threadIdx.x == 0) {
    for (int i = 1; i < 4; ++i) { sum += red[i][0]; ssq += red[i][1]; }
    partial[blockIdx.x * 2] = sum;
    partial[blockIdx.x * 2 + 1] = ssq;
  }
}

// ---------------- LN stats, stage 2 ----------------
__global__ void k_stats2(const double* __restrict__ partial, float* __restrict__ stats) {
  int s = threadIdx.x;  // 64 threads
  double sum = 0.0, ssq = 0.0;
  for (int i = 0; i < 8; ++i) {
    sum += partial[(s * 8 + i) * 2];
    ssq += partial[(s * 8 + i) * 2 + 1];
  }
  double mean = sum / (double)SAMPLE;
  double var = ssq / (double)SAMPLE - mean * mean;
  stats[s * 2] = (float)mean;
  stats[s * 2 + 1] = (float)(1.0 / sqrt(var + (double)LN_EPS));
}

// ---------------- fused LN + MLP + layer-scale + residual ----------------
// 8 waves. LDS (64KB): Ysh [128][256] fp8 swizzled; Tsh [2][128][128] fp8 swizzled.
// Weights consumed as per-lane MFMA fragments straight from global (L2-resident).
__global__ __launch_bounds__(512, 2) void k_fused(
    const float* __restrict__ x, const float* __restrict__ ln_w, const float* __restrict__ ln_b,
    const float* __restrict__ b_in, const float* __restrict__ b_out, const float* __restrict__ gamma,
    const unsigned char* __restrict__ w_in8, const unsigned char* __restrict__ w_out8,
    const float* __restrict__ stats, float* __restrict__ out) {
  extern __shared__ unsigned char smem[];
  unsigned char* Ysh = smem;            // [128][256] fp8
  unsigned char* Tsh = smem + 32768;    // [2][128][128] fp8

  const int tid = threadIdx.x;
  const int s = blockIdx.x >> 4;
  const int p0 = (blockIdx.x & 15) * PB;
  const float mu = stats[s * 2], rstd = stats[s * 2 + 1];
  const float a_ln = rstd, c_ln = -mu * rstd;
  const size_t xbase = (size_t)s * SAMPLE;

  // ---- stage Ysh: normalize + affine, transpose (c,p)->(p,c), cvt fp8 ----
  #pragma unroll
  for (int it = 0; it < 4; ++it) {
    int bid = it * 512 + tid;              // 2048 4x4 micro-blocks
    int c0 = (bid >> 5) * 4, pp = (bid & 31) * 4;
    float yv[4][4];
    #pragma unroll
    for (int i = 0; i < 4; ++i) {
      size_t off = (size_t)(c0 + i) * HW + p0 + pp;
      float4 xv = *(const float4*)(x + xbase + off);
      float4 lw = *(const float4*)(ln_w + off);
      float4 lb = *(const float4*)(ln_b + off);
      yv[i][0] = fmaf(fmaf(xv.x, a_ln, c_ln), lw.x, lb.x);
      yv[i][1] = fmaf(fmaf(xv.y, a_ln, c_ln), lw.y, lb.y);
      yv[i][2] = fmaf(fmaf(xv.z, a_ln, c_ln), lw.z, lb.z);
      yv[i][3] = fmaf(fmaf(xv.w, a_ln, c_ln), lw.w, lb.w);
    }
    #pragma unroll
    for (int j = 0; j < 4; ++j) {
      int p = pp + j;
      int r = __builtin_amdgcn_cvt_pk_fp8_f32(yv[0][j], yv[1][j], 0, false);
      r = __builtin_amdgcn_cvt_pk_fp8_f32(yv[2][j], yv[3][j], r, true);
      *(int*)&Ysh[p * 256 + (c0 ^ swz(p))] = r;
    }
  }

  const int lane = tid & 63, l15 = lane & 15, l4 = lane >> 4;
  const int w = tid >> 6;
  const int wq = w & 1, wp = w >> 1;   // GEMM1: m-block 64*wq, p-block 32*wp
  const int wr = w >> 2, wc = w & 3;   // GEMM2: p-block 64*wr, c-block 64*wc

  f32x4 acc2[4][4] = {};  // persistent 64p x 64c per wave

  __syncthreads();  // Ysh ready

  for (int ch = 0; ch < NCHUNK; ++ch) {
    const int m0 = ch * MC;
    unsigned char* T = Tsh + (ch & 1) * 16384;

    // ---- GEMM1: D1[m][p] = w_in8[m0+..][:] x Ysh^T ; tile 64m x 32p, K=256 ----
    f32x4 acc1[4][2] = {};
    const unsigned char* Arow = w_in8 + (size_t)(m0 + wq * 64 + l15) * CD + l4 * 8;
    #pragma unroll
    for (int kk = 0; kk < 8; ++kk) {
      i64 a[4], b[2];
      #pragma unroll
      for (int mi = 0; mi < 4; ++mi)
        a[mi] = *(const i64*)(Arow + mi * 16 * CD + kk * 32);
      #pragma unroll
      for (int pi = 0; pi < 2; ++pi) {
        int p = wp * 32 + pi * 16 + l15;
        b[pi] = *(const i64*)&Ysh[p * 256 + ((kk * 32 + l4 * 8) ^ swz(p))];
      }
      #pragma unroll
      for (int mi = 0; mi < 4; ++mi)
        #pragma unroll
        for (int pi = 0; pi < 2; ++pi)
          acc1[mi][pi] = __builtin_amdgcn_mfma_f32_16x16x32_fp8_fp8(a[mi], b[pi], acc1[mi][pi], 0, 0, 0);
    }

    // ---- epilogue1: +b_in, fast GELU, pack fp8 -> Tsh[p][m] ----
    #pragma unroll
    for (int mi = 0; mi < 4; ++mi) {
      const int mb = wq * 64 + mi * 16 + l4 * 4;
      const float4 bi = *(const float4*)&b_in[m0 + mb];
      #pragma unroll
      for (int pi = 0; pi < 2; ++pi) {
        int p = wp * 32 + pi * 16 + l15;
        float g[4];
        #pragma unroll
        for (int r = 0; r < 4; ++r) {
          float t = acc1[mi][pi][r] + ((const float*)&bi)[r];
          g[r] = t * __builtin_amdgcn_rcpf(1.0f + __expf(-1.702f * t));
        }
        int pk = __builtin_amdgcn_cvt_pk_fp8_f32(g[0], g[1], 0, false);
        pk = __builtin_amdgcn_cvt_pk_fp8_f32(g[2], g[3], pk, true);
        *(int*)&T[p * 128 + (mb ^ swz(p))] = pk;
      }
    }
    __syncthreads();  // Tsh(ch) ready; also fences next chunk's buffer reuse

    // ---- GEMM2: acc2 += T (128p x 128m) x w_out8 chunk ; tile 64p x 64c ----
    #pragma unroll
    for (int kk = 0; kk < 4; ++kk) {
      i64 a2[4], b2[4];
      #pragma unroll
      for (int mi = 0; mi < 4; ++mi) {
        int p = wr * 64 + mi * 16 + l15;
        a2[mi] = *(const i64*)&T[p * 128 + ((kk * 32 + l4 * 8) ^ swz(p))];
      }
      #pragma unroll
      for (int ni = 0; ni < 4; ++ni)
        b2[ni] = *(const i64*)(w_out8 + (size_t)(wc * 64 + ni * 16 + l15) * MD + m0 + kk * 32 + l4 * 8);
      #pragma unroll
      for (int mi = 0; mi < 4; ++mi)
        #pragma unroll
        for (int ni = 0; ni < 4; ++ni)
          acc2[mi][ni] = __builtin_amdgcn_mfma_f32_16x16x32_fp8_fp8(a2[mi], b2[ni], acc2[mi][ni], 0, 0, 0);
    }
  }

  // ---- epilogue: out = x + gamma_c * (v + b_out_c) ----
  #pragma unroll
  for (int ni = 0; ni < 4; ++ni) {
    int cc = wc * 64 + ni * 16 + l15;
    float gm = gamma[cc], bo = b_out[cc];
    #pragma unroll
    for (int mi = 0; mi < 4; ++mi) {
      int p = p0 + wr * 64 + mi * 16 + l4 * 4;
      size_t off = xbase + (size_t)cc * HW + p;
      float4 xv = *(const float4*)(x + off);
      float4 o;
      #pragma unroll
      for (int r = 0; r < 4; ++r)
        ((float*)&o)[r] = ((const float*)&xv)[r] + gm * (acc2[mi][ni][r] + bo);
      *(float4*)(out + off) = o;
    }
  }
}

extern "C" void kernel_launch(void* const* d_in, const int* in_sizes, int n_in,
                              void* d_out, int out_size, void* d_ws, size_t ws_size,
                              hipStream_t stream) {
  const float* x = (const float*)d_in[0];
  const float* ln_w = (const float*)d_in[1];
  const float* ln_b = (const float*)d_in[2];
  const float* w_in = (const float*)d_in[3];
  const float* b_in = (const float*)d_in[4];
  const float* w_out = (const float*)d_in[5];
  const float* b_out = (const float*)d_in[6];
  const float* gamma = (const float*)d_in[7];
  float* out = (float*)d_out;

  char* ws = (char*)d_ws;
  unsigned char* w_in8 = (unsigned char*)ws;              // 256 KB
  unsigned char* w_out8 = (unsigned char*)(ws + 262144);  // 256 KB
  double* partial = (double*)(ws + 524288);               // 8 KB
  float* stats = (float*)(ws + 524288 + 8192);            // 512 B

  k_prep<<<512, 256, 0, stream>>>(w_in, w_out, w_in8, w_out8);
  k_stats1<<<512, 256, 0, stream>>>(x, partial);
  k_stats2<<<1, 64, 0, stream>>>(partial, stats);

  const int lds_bytes = 65536;  // Ysh 32KB + Tsh 2x16KB
  hipFuncSetAttribute((const void*)k_fused, hipFuncAttributeMaxDynamicSharedMemorySize,
                      lds_bytes);
  k_fused<<<1024, 512, lds_bytes, stream>>>(x, ln_w, ln_b, b_in, b_out, gamma,
                                            w_in8, w_out8, stats, out);
}

// Round 3
// 306.704 us; speedup vs baseline: 1.5631x; 1.5631x over previous
//
#include <hip/hip_runtime.h>
#include <math.h>

// x: (4,16,256,32,64) f32 -> NS=64 samples, CD=256 channels, HW=2048 positions
#define NS 64
#define CD 256
#define HW 2048
#define MD 1024
#define SAMPLE (CD * HW)
#define LN_EPS 1e-5f

#define PB 64            // positions per block
#define MC 128           // m-chunk
#define NCHUNK (MD / MC) // 8

typedef float f32x4 __attribute__((ext_vector_type(4)));
typedef long i64;

// XOR swizzle key: byte-bits 4-6. Verified 2-way-max for all access patterns here.
__device__ __forceinline__ int swz(int p) { return ((p ^ (p >> 2)) & 7) << 4; }

// ---------------- weight prep: f32 -> fp8 e4m3, transposed ----------------
__global__ __launch_bounds__(256) void k_prep(const float* __restrict__ w_in,
                                              const float* __restrict__ w_out,
                                              unsigned char* __restrict__ w_in8,
                                              unsigned char* __restrict__ w_out8) {
  int id = blockIdx.x * 256 + threadIdx.x;  // 0..131071
  if (id < 65536) {
    int m = id >> 6, c0 = (id & 63) * 4;
    float a = w_in[(size_t)(c0 + 0) * MD + m];
    float b = w_in[(size_t)(c0 + 1) * MD + m];
    float c = w_in[(size_t)(c0 + 2) * MD + m];
    float d = w_in[(size_t)(c0 + 3) * MD + m];
    int r = __builtin_amdgcn_cvt_pk_fp8_f32(a, b, 0, false);
    r = __builtin_amdgcn_cvt_pk_fp8_f32(c, d, r, true);
    ((int*)w_in8)[id] = r;  // [m][c]
  } else {
    int j = id - 65536;
    int c = j >> 8, m0 = (j & 255) * 4;
    float a = w_out[(size_t)(m0 + 0) * CD + c];
    float b = w_out[(size_t)(m0 + 1) * CD + c];
    float cc = w_out[(size_t)(m0 + 2) * CD + c];
    float d = w_out[(size_t)(m0 + 3) * CD + c];
    int r = __builtin_amdgcn_cvt_pk_fp8_f32(a, b, 0, false);
    r = __builtin_amdgcn_cvt_pk_fp8_f32(cc, d, r, true);
    ((int*)w_out8)[j] = r;  // [c][m]
  }
}

// ---------------- LN stats, stage 1 ----------------
__global__ __launch_bounds__(256) void k_stats1(const float* __restrict__ x,
                                                double* __restrict__ partial) {
  int s = blockIdx.x >> 3, sl = blockIdx.x & 7;
  const float4* p = (const float4*)(x + (size_t)s * SAMPLE + (size_t)sl * 65536);
  double sum = 0.0, ssq = 0.0;
  for (int i = 0; i < 64; ++i) {
    float4 v = p[i * 256 + threadIdx.x];
    sum += (double)v.x + (double)v.y + (double)v.z + (double)v.w;
    ssq += (double)v.x * v.x + (double)v.y * v.y + (double)v.z * v.z + (double)v.w * v.w;
  }
  for (int off = 32; off; off >>= 1) {
    sum += __shfl_down(sum, off);
    ssq += __shfl_down(ssq, off);
  }
  __shared__ double red[4][2];
  int wv = threadIdx.x >> 6, ln = threadIdx.x & 63;
  if (ln == 0) { red[wv][0] = sum; red[wv][1] = ssq; }
  __syncthreads();
  if (threadIdx.x == 0) {
    for (int i = 1; i < 4; ++i) { sum += red[i][0]; ssq += red[i][1]; }
    partial[blockIdx.x * 2] = sum;
    partial[blockIdx.x * 2 + 1] = ssq;
  }
}

// ---------------- LN stats, stage 2 ----------------
__global__ void k_stats2(const double* __restrict__ partial, float* __restrict__ stats) {
  int s = threadIdx.x;  // 64 threads
  double sum = 0.0, ssq = 0.0;
  for (int i = 0; i < 8; ++i) {
    sum += partial[(s * 8 + i) * 2];
    ssq += partial[(s * 8 + i) * 2 + 1];
  }
  double mean = sum / (double)SAMPLE;
  double var = ssq / (double)SAMPLE - mean * mean;
  stats[s * 2] = (float)mean;
  stats[s * 2 + 1] = (float)(1.0 / sqrt(var + (double)LN_EPS));
}

// ---------------- fused LN + MLP + layer-scale + residual ----------------
// PB=64 positions/block, 2048 blocks, 8 waves. LDS 32KB -> 2 blocks/CU at <=128 VGPR.
// Wave w owns: GEMM1 m-rows [16w,16w+16); GEMM2 c-cols [32w,32w+32). Zero wave
// duplication of global weight-fragment traffic; frags batched into regs up-front.
__global__ __launch_bounds__(512, 4) void k_fused(
    const float* __restrict__ x, const float* __restrict__ ln_w, const float* __restrict__ ln_b,
    const float* __restrict__ b_in, const float* __restrict__ b_out, const float* __restrict__ gamma,
    const unsigned char* __restrict__ w_in8, const unsigned char* __restrict__ w_out8,
    const float* __restrict__ stats, float* __restrict__ out) {
  __shared__ unsigned char Ysh[64 * 256];       // [p][c] fp8, swizzled
  __shared__ unsigned char Tsh[2][64 * 128];    // [p][m] fp8, swizzled, dbuf

  const int tid = threadIdx.x;
  const int s = blockIdx.x >> 5;
  const int p0 = (blockIdx.x & 31) * PB;
  const float mu = stats[s * 2], rstd = stats[s * 2 + 1];
  const float a_ln = rstd, c_ln = -mu * rstd;
  const size_t xbase = (size_t)s * SAMPLE;

  // ---- stage Ysh: normalize + affine, transpose (c,p)->(p,c), cvt fp8 ----
  #pragma unroll
  for (int it = 0; it < 2; ++it) {
    int bid = it * 512 + tid;               // 1024 4x4 micro-blocks
    int c0 = (bid >> 4) * 4, pp = (bid & 15) * 4;
    float yv[4][4];
    #pragma unroll
    for (int i = 0; i < 4; ++i) {
      size_t off = (size_t)(c0 + i) * HW + p0 + pp;
      float4 xv = *(const float4*)(x + xbase + off);
      float4 lw = *(const float4*)(ln_w + off);
      float4 lb = *(const float4*)(ln_b + off);
      yv[i][0] = fmaf(fmaf(xv.x, a_ln, c_ln), lw.x, lb.x);
      yv[i][1] = fmaf(fmaf(xv.y, a_ln, c_ln), lw.y, lb.y);
      yv[i][2] = fmaf(fmaf(xv.z, a_ln, c_ln), lw.z, lb.z);
      yv[i][3] = fmaf(fmaf(xv.w, a_ln, c_ln), lw.w, lb.w);
    }
    #pragma unroll
    for (int j = 0; j < 4; ++j) {
      int p = pp + j;
      int r = __builtin_amdgcn_cvt_pk_fp8_f32(yv[0][j], yv[1][j], 0, false);
      r = __builtin_amdgcn_cvt_pk_fp8_f32(yv[2][j], yv[3][j], r, true);
      *(int*)&Ysh[p * 256 + (c0 ^ swz(p))] = r;
    }
  }

  const int lane = tid & 63, l15 = lane & 15, l4 = lane >> 4;
  const int w = tid >> 6;

  f32x4 acc2[4][2] = {};  // 64p x 32c per wave, persistent

  __syncthreads();  // Ysh ready

  const unsigned char* Arow = w_in8 + (size_t)(16 * w + l15) * CD + l4 * 8;
  const unsigned char* Brow = w_out8 + (size_t)(32 * w + l15) * MD + l4 * 8;
  const float4 bi_all[2] = {};  // placeholder removed

  for (int ch = 0; ch < NCHUNK; ++ch) {
    const int m0 = ch * MC;
    unsigned char* T = Tsh[ch & 1];

    // ---- GEMM1: D1[m][p], wave slice 16m x 64p, K=256 ----
    i64 a[8];
    #pragma unroll
    for (int kk = 0; kk < 8; ++kk)
      a[kk] = *(const i64*)(Arow + (size_t)m0 * CD + kk * 32);
    f32x4 acc1[4] = {};
    #pragma unroll
    for (int kk = 0; kk < 8; ++kk) {
      #pragma unroll
      for (int pi = 0; pi < 4; ++pi) {
        int p = pi * 16 + l15;
        i64 b = *(const i64*)&Ysh[p * 256 + ((kk * 32 + l4 * 8) ^ swz(p))];
        acc1[pi] = __builtin_amdgcn_mfma_f32_16x16x32_fp8_fp8(a[kk], b, acc1[pi], 0, 0, 0);
      }
    }

    // ---- epilogue1: +b_in, sigmoid-GELU, pack fp8 -> Tsh[p][m] ----
    const float4 bi = *(const float4*)&b_in[m0 + 16 * w + 4 * l4];
    const int mcol = 16 * w + 4 * l4;
    #pragma unroll
    for (int pi = 0; pi < 4; ++pi) {
      int p = pi * 16 + l15;
      float g[4];
      #pragma unroll
      for (int r = 0; r < 4; ++r) {
        float t = acc1[pi][r] + ((const float*)&bi)[r];
        g[r] = t * __builtin_amdgcn_rcpf(1.0f + __expf(-1.702f * t));
      }
      int pk = __builtin_amdgcn_cvt_pk_fp8_f32(g[0], g[1], 0, false);
      pk = __builtin_amdgcn_cvt_pk_fp8_f32(g[2], g[3], pk, true);
      *(int*)&T[p * 128 + (mcol ^ swz(p))] = pk;
    }

    // ---- GEMM2 B-frags from global, issued BEFORE the barrier ----
    i64 b2[2][4];
    #pragma unroll
    for (int ni = 0; ni < 2; ++ni)
      #pragma unroll
      for (int kk = 0; kk < 4; ++kk)
        b2[ni][kk] = *(const i64*)(Brow + (size_t)ni * 16 * MD + m0 + kk * 32);

    __syncthreads();  // Tsh(ch) ready

    // ---- GEMM2: acc2 += T (64p x 128m) x w_out chunk; wave slice 64p x 32c ----
    #pragma unroll
    for (int kk = 0; kk < 4; ++kk) {
      i64 a2[4];
      #pragma unroll
      for (int mi = 0; mi < 4; ++mi) {
        int p = mi * 16 + l15;
        a2[mi] = *(const i64*)&T[p * 128 + ((kk * 32 + l4 * 8) ^ swz(p))];
      }
      #pragma unroll
      for (int mi = 0; mi < 4; ++mi)
        #pragma unroll
        for (int ni = 0; ni < 2; ++ni)
          acc2[mi][ni] = __builtin_amdgcn_mfma_f32_16x16x32_fp8_fp8(a2[mi], b2[ni][kk], acc2[mi][ni], 0, 0, 0);
    }
  }

  // ---- epilogue: out = x + gamma_c * (v + b_out_c) ----
  #pragma unroll
  for (int ni = 0; ni < 2; ++ni) {
    int cc = 32 * w + 16 * ni + l15;
    float gm = gamma[cc], bo = b_out[cc];
    #pragma unroll
    for (int mi = 0; mi < 4; ++mi) {
      int p = p0 + 16 * mi + 4 * l4;
      size_t off = xbase + (size_t)cc * HW + p;
      float4 xv = *(const float4*)(x + off);
      float4 o;
      #pragma unroll
      for (int r = 0; r < 4; ++r)
        ((float*)&o)[r] = ((const float*)&xv)[r] + gm * (acc2[mi][ni][r] + bo);
      *(float4*)(out + off) = o;
    }
  }
}

extern "C" void kernel_launch(void* const* d_in, const int* in_sizes, int n_in,
                              void* d_out, int out_size, void* d_ws, size_t ws_size,
                              hipStream_t stream) {
  const float* x = (const float*)d_in[0];
  const float* ln_w = (const float*)d_in[1];
  const float* ln_b = (const float*)d_in[2];
  const float* w_in = (const float*)d_in[3];
  const float* b_in = (const float*)d_in[4];
  const float* w_out = (const float*)d_in[5];
  const float* b_out = (const float*)d_in[6];
  const float* gamma = (const float*)d_in[7];
  float* out = (float*)d_out;

  char* ws = (char*)d_ws;
  unsigned char* w_in8 = (unsigned char*)ws;              // 256 KB [m][c]
  unsigned char* w_out8 = (unsigned char*)(ws + 262144);  // 256 KB [c][m]
  double* partial = (double*)(ws + 524288);               // 8 KB
  float* stats = (float*)(ws + 524288 + 8192);            // 512 B

  k_prep<<<512, 256, 0, stream>>>(w_in, w_out, w_in8, w_out8);
  k_stats1<<<512, 256, 0, stream>>>(x, partial);
  k_stats2<<<1, 64, 0, stream>>>(partial, stats);

  k_fused<<<2048, 512, 0, stream>>>(x, ln_w, ln_b, b_in, b_out, gamma,
                                    w_in8, w_out8, stats, out);
}